// Round 1
// 182.133 us; speedup vs baseline: 1.0038x; 1.0038x over previous
//
#include <hip/hip_runtime.h>
#include <math.h>

#define N_S   1024
#define N_T   1024
#define C_IN  128
#define E_EDG 16384
#define R     32
#define NSTEP 2

// ---------------------------------------------------------------------------
// k_pre: G[a,b] = sum_c W1[a,c]W1[b,c] + W2[a,c]W2[b,c]  (coalesced via LDS
// transpose staging) + zero rt/aggt/aggs0/aggs1 (zbuf = 131072 floats).
// grid 128 x 256
// ---------------------------------------------------------------------------
__global__ __launch_bounds__(256) void k_pre(const float* __restrict__ W1,
                                             const float* __restrict__ W2,
                                             float* __restrict__ G,
                                             float* __restrict__ zbuf) {
    int t = threadIdx.x;
    ((float4*)zbuf)[blockIdx.x * 256 + t] = make_float4(0.f, 0.f, 0.f, 0.f);

    int a = blockIdx.x;
    __shared__ float wa[512];
    __shared__ float wt[64][129];   // wt[c][b], pad 129 -> 2-way max on write
    __shared__ float red[256];
    for (int s = t; s < 512; s += 256)
        wa[s] = (s < 256) ? W1[a * 256 + s] : W2[a * 256 + (s - 256)];
    __syncthreads();

    float acc = 0.f;
    int b = t & 127, h = t >> 7;
    for (int ci = 0; ci < 8; ++ci) {
        const float* Wsrc = (ci < 4) ? W1 : W2;
        int cbase = (ci < 4) ? ci * 64 : (ci - 4) * 64;
#pragma unroll
        for (int it = 0; it < 8; ++it) {
            int s = it * 256 + t;
            int br = s >> 4, q = s & 15;
            float4 v = *(const float4*)(Wsrc + (size_t)br * 256 + cbase + q * 4);
            wt[q * 4 + 0][br] = v.x; wt[q * 4 + 1][br] = v.y;
            wt[q * 4 + 2][br] = v.z; wt[q * 4 + 3][br] = v.w;
        }
        __syncthreads();
        const float* wac = wa + ci * 64 + h * 32;
#pragma unroll
        for (int cc = 0; cc < 32; ++cc)
            acc += wac[cc] * wt[h * 32 + cc][b];
        __syncthreads();
    }
    red[t] = acc;
    __syncthreads();
    if (t < 128) G[a * 128 + t] = red[t] + red[t + 128];
}

// ---------------------------------------------------------------------------
// Ys[i,a] = sum_d inputs[idx1[i],d] * G[d,a]
// ---------------------------------------------------------------------------
__global__ __launch_bounds__(128) void k_ys(const float* __restrict__ X,
                                            const int* __restrict__ idx1,
                                            const float* __restrict__ G,
                                            float* __restrict__ Ys) {
    int i = blockIdx.x;
    int a = threadIdx.x;
    __shared__ float x[128];
    int row = idx1[i];
    x[a] = X[row * 128 + a];
    __syncthreads();
    float acc = 0.f;
#pragma unroll 8
    for (int d = 0; d < 128; ++d)
        acc += x[d] * G[d * 128 + a];
    Ys[i * 128 + a] = acc;
}

// ---------------------------------------------------------------------------
// Shat[i,j] = Ys[i,:] . X[idx2[j],:]  (64x64 tile) + per-(row,jtile) softmax
// partials part[row][jt] = (tileMax, tileSumExp)
// ---------------------------------------------------------------------------
__global__ __launch_bounds__(256) void k_shat(const float* __restrict__ Ys,
                                              const float* __restrict__ X,
                                              const int* __restrict__ idx2,
                                              float* __restrict__ Shat,
                                              float2* __restrict__ part) {
    __shared__ float As[64][132];
    __shared__ float Bs[64][132];
    const int i0 = blockIdx.y * 64, j0 = blockIdx.x * 64;
    const int t = threadIdx.x;
    for (int s = t; s < 64 * 32; s += 256) {
        int row = s >> 5, q = s & 31;
        float4 v = ((const float4*)(Ys + (size_t)(i0 + row) * 128))[q];
        *(float4*)&As[row][q * 4] = v;
    }
    for (int s = t; s < 64 * 32; s += 256) {
        int row = s >> 5, q = s & 31;
        int src = idx2[j0 + row];
        float4 v = ((const float4*)(X + (size_t)src * 128))[q];
        *(float4*)&Bs[row][q * 4] = v;
    }
    __syncthreads();
    const int r = t >> 4, c = t & 15;
    float acc[4][4] = {};
    for (int k = 0; k < 128; k += 4) {
        float4 ya[4], xb[4];
#pragma unroll
        for (int a = 0; a < 4; ++a) ya[a] = *(const float4*)&As[r + 16 * a][k];
#pragma unroll
        for (int b = 0; b < 4; ++b) xb[b] = *(const float4*)&Bs[c + 16 * b][k];
#pragma unroll
        for (int a = 0; a < 4; ++a)
#pragma unroll
            for (int b = 0; b < 4; ++b)
                acc[a][b] += ya[a].x * xb[b].x + ya[a].y * xb[b].y +
                             ya[a].z * xb[b].z + ya[a].w * xb[b].w;
    }
#pragma unroll
    for (int a = 0; a < 4; ++a) {
#pragma unroll
        for (int b = 0; b < 4; ++b)
            Shat[(size_t)(i0 + r + 16 * a) * 1024 + (j0 + c + 16 * b)] = acc[a][b];
        float M = fmaxf(fmaxf(acc[a][0], acc[a][1]), fmaxf(acc[a][2], acc[a][3]));
#pragma unroll
        for (int m = 1; m < 16; m <<= 1) M = fmaxf(M, __shfl_xor(M, m, 16));
        float Ss = 0.f;
#pragma unroll
        for (int b = 0; b < 4; ++b) Ss += __expf(acc[a][b] - M);
#pragma unroll
        for (int m = 1; m < 16; m <<= 1) Ss += __shfl_xor(Ss, m, 16);
        if (c == 0)
            part[(size_t)(i0 + r + 16 * a) * 16 + blockIdx.x] = make_float2(M, Ss);
    }
}

// ---------------------------------------------------------------------------
// s-graph scatter for BOTH steps: aggs_step[dst] += rs_step[src]
// grid 4096 x 256
// ---------------------------------------------------------------------------
__global__ __launch_bounds__(256) void k_scat_s(const int* __restrict__ es,
                                                const float* __restrict__ rs_all,
                                                float* __restrict__ aggs0,
                                                float* __restrict__ aggs1) {
    int gid = blockIdx.x * 256 + threadIdx.x;
    int k = gid & 31;
    int ei = gid >> 5;              // 0..32767
    int step = ei >> 14;
    int e = ei & (E_EDG - 1);
    int src = es[e], dst = es[E_EDG + e];
    const float* rs = rs_all + (size_t)step * N_S * R;
    float* aggs = step ? aggs1 : aggs0;
    atomicAdd(&aggs[(size_t)dst * 32 + k], rs[(size_t)src * 32 + k]);
}

// ---------------------------------------------------------------------------
// P_step = relu((rs+aggs)@W3+b3) @ Wm1 + bm1 for both steps (2048 rows)
// grid 256 x 256 (8 rows/block)
// ---------------------------------------------------------------------------
__global__ __launch_bounds__(256) void k_post_s(const float* __restrict__ rs_all,
                                                const float* __restrict__ aggs0,
                                                const float* __restrict__ aggs1,
                                                const float* __restrict__ W3,
                                                const float* __restrict__ b3,
                                                const float* __restrict__ Wm1,
                                                const float* __restrict__ bm1,
                                                float* __restrict__ P0,
                                                float* __restrict__ P1) {
    __shared__ float w3[1024], wm1[1024];
    __shared__ float ul[8][33], ol[8][33];
    int t = threadIdx.x;
    for (int s = t; s < 1024; s += 256) { w3[s] = W3[s]; wm1[s] = Wm1[s]; }
    int row8 = t >> 5, k = t & 31;
    int grow = blockIdx.x * 8 + row8;          // 0..2047
    int step = grow >> 10;
    int r = grow & 1023;
    const float* rs = rs_all + (size_t)step * N_S * R;
    const float* agg = step ? aggs1 : aggs0;
    float* P = step ? P1 : P0;
    ul[row8][k] = rs[(size_t)r * 32 + k] + agg[(size_t)r * 32 + k];
    __syncthreads();
    float acc = b3[k];
#pragma unroll
    for (int m = 0; m < 32; ++m) acc += ul[row8][m] * w3[m * 32 + k];
    ol[row8][k] = fmaxf(acc, 0.f);
    __syncthreads();
    float acc2 = bm1[k];
#pragma unroll
    for (int m = 0; m < 32; ++m) acc2 += ol[row8][m] * wm1[m * 32 + k];
    P[(size_t)r * 32 + k] = acc2;
}

// ---------------------------------------------------------------------------
// rt[j,k] += sum_i softmax(Shat)[i,j] * rs[i,k]; softmax computed inline from
// merged tile partials; at step 0 also writes S_0 to out0.
// grid (16 jt, 8 ic) x 256
// ---------------------------------------------------------------------------
__global__ __launch_bounds__(256) void k_rt(const float* __restrict__ Shat,
                                            const float2* __restrict__ part,
                                            const float* __restrict__ rs,
                                            float* __restrict__ rt,
                                            float* __restrict__ out0) {
    int j0 = blockIdx.x * 64;
    int i0 = blockIdx.y * 128;
    int t = threadIdx.x;
    __shared__ float Sl[16][68];
    __shared__ float Rl[16][36];
    __shared__ float mrow[128], irow[128];
    if (t < 128) {
        const float2* pr = part + (size_t)(i0 + t) * 16;
        float M = -1e30f, S = 0.f;
        float2 ps[16];
#pragma unroll
        for (int q = 0; q < 16; ++q) { ps[q] = pr[q]; M = fmaxf(M, ps[q].x); }
#pragma unroll
        for (int q = 0; q < 16; ++q) S += ps[q].y * __expf(ps[q].x - M);
        mrow[t] = M;
        irow[t] = 1.f / S;
    }
    __syncthreads();
    int k = t & 31, jg = t >> 5;
    float acc[8] = {};
    for (int ic = 0; ic < 128; ic += 16) {
        for (int s = t; s < 16 * 16; s += 256) {
            int row = s >> 4, q = s & 15;
            int lr = ic + row;
            float4 v = ((const float4*)(Shat + (size_t)(i0 + lr) * 1024 + j0))[q];
            float m = mrow[lr], inv = irow[lr];
            v.x = __expf(v.x - m) * inv;
            v.y = __expf(v.y - m) * inv;
            v.z = __expf(v.z - m) * inv;
            v.w = __expf(v.w - m) * inv;
            *(float4*)&Sl[row][q * 4] = v;
            if (out0)
                ((float4*)(out0 + (size_t)(i0 + lr) * 1024 + j0))[q] = v;
        }
        for (int s = t; s < 16 * 8; s += 256) {
            int row = s >> 3, q = s & 7;
            *(float4*)&Rl[row][q * 4] =
                ((const float4*)(rs + (size_t)(i0 + ic + row) * 32))[q];
        }
        __syncthreads();
#pragma unroll
        for (int ii = 0; ii < 16; ++ii) {
            float rv = Rl[ii][k];
#pragma unroll
            for (int m = 0; m < 8; ++m)
                acc[m] += Sl[ii][jg * 8 + m] * rv;
        }
        __syncthreads();
    }
#pragma unroll
    for (int m = 0; m < 8; ++m)
        atomicAdd(&rt[(size_t)(j0 + jg * 8 + m) * 32 + k], acc[m]);
}

// ---------------------------------------------------------------------------
// t-graph scatter: aggt[dst] += rt[src].  grid 2048 x 256
// ---------------------------------------------------------------------------
__global__ __launch_bounds__(256) void k_scat_t(const int* __restrict__ et,
                                                const float* __restrict__ rt,
                                                float* __restrict__ aggt) {
    int gid = blockIdx.x * 256 + threadIdx.x;
    int k = gid & 31;
    int e = gid >> 5;
    int src = et[e], dst = et[E_EDG + e];
    atomicAdd(&aggt[(size_t)dst * 32 + k], rt[(size_t)src * 32 + k]);
}

// ---------------------------------------------------------------------------
// Q = relu((rt+aggt)@W3+b3) @ Wm1   (no bm1).  grid 128 x 256
// ---------------------------------------------------------------------------
__global__ __launch_bounds__(256) void k_post_t(const float* __restrict__ rt,
                                                const float* __restrict__ aggt,
                                                const float* __restrict__ W3,
                                                const float* __restrict__ b3,
                                                const float* __restrict__ Wm1,
                                                float* __restrict__ Q) {
    __shared__ float w3[1024], wm1[1024];
    __shared__ float ul[8][33], ol[8][33];
    int t = threadIdx.x;
    for (int s = t; s < 1024; s += 256) { w3[s] = W3[s]; wm1[s] = Wm1[s]; }
    int row8 = t >> 5, k = t & 31;
    int r = blockIdx.x * 8 + row8;             // 0..1023
    ul[row8][k] = rt[(size_t)r * 32 + k] + aggt[(size_t)r * 32 + k];
    __syncthreads();
    float acc = b3[k];
#pragma unroll
    for (int m = 0; m < 32; ++m) acc += ul[row8][m] * w3[m * 32 + k];
    ol[row8][k] = fmaxf(acc, 0.f);
    __syncthreads();
    float acc2 = 0.f;
#pragma unroll
    for (int m = 0; m < 32; ++m) acc2 += ol[row8][m] * wm1[m * 32 + k];
    Q[(size_t)r * 32 + k] = acc2;
}

// ---------------------------------------------------------------------------
// Shat += bm2 + sum_k Wm2[k]*relu(P[i,k]-Q[j,k]); emits new softmax partials;
// blockIdx.y==0 blocks also zero rt+aggt for the next step.
// grid (16,16) x 256
// ---------------------------------------------------------------------------
__global__ __launch_bounds__(256) void k_delta(const float* __restrict__ P,
                                               const float* __restrict__ Q,
                                               const float* __restrict__ Wm2,
                                               const float* __restrict__ bm2,
                                               float* __restrict__ Shat,
                                               float2* __restrict__ part,
                                               float* __restrict__ zbuf) {
    __shared__ float Pl[64][36], Ql[64][36];
    int t = threadIdx.x;
    if (blockIdx.y == 0) {
        float4 z = make_float4(0.f, 0.f, 0.f, 0.f);
        float4* zb = (float4*)zbuf;
        int base = (blockIdx.x * 256 + t) * 4;     // 16 blocks * 1024 = 16384 float4
#pragma unroll
        for (int q = 0; q < 4; ++q) zb[base + q] = z;
    }
    int i0 = blockIdx.y * 64, j0 = blockIdx.x * 64;
    for (int s = t; s < 64 * 8; s += 256) {
        int row = s >> 3, q = s & 7;
        *(float4*)&Pl[row][q * 4] = ((const float4*)(P + (size_t)(i0 + row) * 32))[q];
        *(float4*)&Ql[row][q * 4] = ((const float4*)(Q + (size_t)(j0 + row) * 32))[q];
    }
    __syncthreads();
    int r = t >> 4, c = t & 15;
    float bv = bm2[0];
    float acc[4][4] = {};
#pragma unroll
    for (int q = 0; q < 8; ++q) {
        float4 w = ((const float4*)Wm2)[q];
        float4 pa[4], qb[4];
#pragma unroll
        for (int a = 0; a < 4; ++a) pa[a] = *(const float4*)&Pl[r + 16 * a][q * 4];
#pragma unroll
        for (int b = 0; b < 4; ++b) qb[b] = *(const float4*)&Ql[c + 16 * b][q * 4];
#pragma unroll
        for (int a = 0; a < 4; ++a)
#pragma unroll
            for (int b = 0; b < 4; ++b)
                acc[a][b] += w.x * fmaxf(pa[a].x - qb[b].x, 0.f)
                           + w.y * fmaxf(pa[a].y - qb[b].y, 0.f)
                           + w.z * fmaxf(pa[a].z - qb[b].z, 0.f)
                           + w.w * fmaxf(pa[a].w - qb[b].w, 0.f);
    }
#pragma unroll
    for (int a = 0; a < 4; ++a) {
        float v[4];
#pragma unroll
        for (int b = 0; b < 4; ++b) {
            size_t idx = (size_t)(i0 + r + 16 * a) * 1024 + (j0 + c + 16 * b);
            v[b] = Shat[idx] + acc[a][b] + bv;
            Shat[idx] = v[b];
        }
        float M = fmaxf(fmaxf(v[0], v[1]), fmaxf(v[2], v[3]));
#pragma unroll
        for (int m = 1; m < 16; m <<= 1) M = fmaxf(M, __shfl_xor(M, m, 16));
        float Ss = 0.f;
#pragma unroll
        for (int b = 0; b < 4; ++b) Ss += __expf(v[b] - M);
#pragma unroll
        for (int m = 1; m < 16; m <<= 1) Ss += __shfl_xor(Ss, m, 16);
        if (c == 0)
            part[(size_t)(i0 + r + 16 * a) * 16 + blockIdx.x] = make_float2(M, Ss);
    }
}

// ---------------------------------------------------------------------------
// Final softmax from partials: out2[i,:] = exp(Shat[i,:]-M)*inv
// grid 1024 x 256
// ---------------------------------------------------------------------------
__global__ __launch_bounds__(256) void k_fsm(const float* __restrict__ Shat,
                                             const float2* __restrict__ part,
                                             float* __restrict__ out2) {
    int i = blockIdx.x, t = threadIdx.x;
    const float2* pr = part + (size_t)i * 16;
    float M = -1e30f, S = 0.f;
    float2 ps[16];
#pragma unroll
    for (int q = 0; q < 16; ++q) { ps[q] = pr[q]; M = fmaxf(M, ps[q].x); }
#pragma unroll
    for (int q = 0; q < 16; ++q) S += ps[q].y * __expf(ps[q].x - M);
    float inv = 1.f / S;
    const float* row = Shat + (size_t)i * 1024;
#pragma unroll
    for (int j = 0; j < 4; ++j)
        out2[(size_t)i * 1024 + t + 256 * j] = __expf(row[t + 256 * j] - M) * inv;
}

// ---------------------------------------------------------------------------
extern "C" void kernel_launch(void* const* d_in, const int* in_sizes, int n_in,
                              void* d_out, int out_size, void* d_ws, size_t ws_size,
                              hipStream_t stream) {
    const float* inputs = (const float*)d_in[0];
    const int*   idx1   = (const int*)d_in[1];
    const int*   idx2   = (const int*)d_in[2];
    const int*   es     = (const int*)d_in[3];
    const int*   et     = (const int*)d_in[4];
    const float* W1     = (const float*)d_in[5];
    const float* W2     = (const float*)d_in[6];
    const float* W3     = (const float*)d_in[7];
    const float* b3     = (const float*)d_in[8];
    const float* Wm1    = (const float*)d_in[9];
    const float* bm1    = (const float*)d_in[10];
    const float* Wm2    = (const float*)d_in[11];
    const float* bm2    = (const float*)d_in[12];
    const float* rs_all = (const float*)d_in[13];
    float* out = (float*)d_out;
    float* ws  = (float*)d_ws;

    // workspace layout (floats)
    float*  Shat  = ws;                       // 1,048,576
    float*  Ys    = Shat + (1 << 20);         // 131,072
    float*  G     = Ys + 131072;              // 16,384
    float2* part  = (float2*)(G + 16384);     // 32,768 floats (1024x16 float2)
    float*  rt    = G + 16384 + 32768;        // 32,768  ┐ contiguous zero range
    float*  aggt  = rt + 32768;               // 32,768  │ (rt..aggs1, 131072)
    float*  aggs0 = aggt + 32768;             // 32,768  │
    float*  aggs1 = aggs0 + 32768;            // 32,768  ┘
    float*  P0    = aggs1 + 32768;            // 32,768
    float*  P1    = P0 + 32768;               // 32,768
    float*  Q     = P1 + 32768;               // 32,768

    k_pre<<<128, 256, 0, stream>>>(W1, W2, G, rt);
    k_ys<<<1024, 128, 0, stream>>>(inputs, idx1, G, Ys);
    k_shat<<<dim3(16, 16), 256, 0, stream>>>(Ys, inputs, idx2, Shat, part);
    k_scat_s<<<4096, 256, 0, stream>>>(es, rs_all, aggs0, aggs1);
    k_post_s<<<256, 256, 0, stream>>>(rs_all, aggs0, aggs1, W3, b3, Wm1, bm1, P0, P1);

    for (int step = 0; step < NSTEP; ++step) {
        const float* rs = rs_all + (size_t)step * N_S * R;
        k_rt<<<dim3(16, 8), 256, 0, stream>>>(Shat, part, rs, rt,
                                              step == 0 ? out : nullptr);
        k_scat_t<<<2048, 256, 0, stream>>>(et, rt, aggt);
        k_post_t<<<128, 256, 0, stream>>>(rt, aggt, W3, b3, Wm1, Q);
        k_delta<<<dim3(16, 16), 256, 0, stream>>>(step ? P1 : P0, Q, Wm2, bm2,
                                                  Shat, part, rt);
    }
    k_fsm<<<1024, 256, 0, stream>>>(Shat, part, out + (1 << 20));
}